// Round 9
// baseline (117.829 us; speedup 1.0000x reference)
//
#include <hip/hip_runtime.h>
#include <hip/hip_bf16.h>

// ---------------------------------------------------------------------------
// DisNet: clf CE + NN distill + multi-kernel MMD. THREE dispatches, no memset,
// ZERO device fences; cross-kernel visibility = dispatch boundaries.
// Ledger (prev session): node boundary ~7-10 us; cooperative launch fails this
// harness; judge k3 levers by counter RATIOS not dur_us (clock-band variance).
// ROUND LEDGER (this session):
//   R1 FAILED: (256,4) on 128x128/acc[4][4] -> acc spilled (WRITE 1->107MB).
//     64 AGPR acc + epilogue needs >=144 regs at 4 waves/SIMD.
//   R2 WIN: (256,3) + epilogue cuts -> total 115.7.
//   R3 WIN: packed-fp32 epilogue + ssq hoist + uniform tri branch -> 113.5.
//   R4 FAILED: 128x64 tile -> per-BLOCK fixed overhead doubled per FLOP.
//   R5 FAILED: k4-into-k3 fusion -> extends critical dispatch (46->83us).
//   R6 NEUTRAL-NEG: explicit dbuf BK=32 -> compiler already overlaps; 2x bar.
//   R7 WIN: setprio around MFMA (T5 independent-block shape) -> 111.9. BEST.
//   R8 WIN-ish: diag-pack + full unroll -> k3 45.0us, total 112.9 (in band).
//   R9: 8-wave 128^2 k3 (512 thr). Same tile/barriers/staging (R4's failure
//     mechanism absent); per-wave acc halves to acc[4][2]=32 AGPR so the
//     128-reg cap for 4 waves/SIMD is feasible (R1's failure mechanism
//     removed at the root). 12 -> 16 waves/CU. KILL: WRITE_SIZE >> 1.1MB
//     (spill) or k3 > 48us -> revert to R8 = practical ceiling.
//   kA      : fp32->bf16 convert + row sq-norms + argmin-key inits + per-
//             block ssq partial; block 0 zeroes accD + cnts
//   k3_mfma : pairwise gram, linear 2080-block grid (1024 XY + 528 XX + 528
//             YY upper-tri), LDS staging (global_load_lds w=16, XOR swizzle,
//             0 bank conflicts), MFMA 16x16x32 bf16, packed-fp32 exp-squaring
//             RBF epilogue, packed-u32 argmin, setprio around MFMA.
//   k4      : 17 blocks: 16 workers CE + distill partials (atomics), barrier-
//             drained counter bump; block 16 polls and finalizes out[] via
//             ATOMIC accD reads (per-XCD L2 not coherent for plain loads)
// ---------------------------------------------------------------------------

#define NS 4096
#define D  256
#define C  6

typedef unsigned int u32;
typedef unsigned short u16;
typedef __attribute__((ext_vector_type(8))) short short8;
typedef __attribute__((ext_vector_type(8))) unsigned short ushort8v;
typedef __attribute__((ext_vector_type(4))) float floatx4;
typedef __attribute__((ext_vector_type(2))) float float2v;   // -> v_pk_*_f32

#define EXP2F(x) __builtin_amdgcn_exp2f(x)   // v_exp_f32: D = 2^S0

#define GLD_LDS16(g, l)                                                        \
    __builtin_amdgcn_global_load_lds(                                          \
        (const __attribute__((address_space(1))) unsigned int*)(g),            \
        (__attribute__((address_space(3))) unsigned int*)(l), 16, 0, 0)

__device__ inline u16 f2bf(float f) {
    unsigned u = __float_as_uint(f);
    return (u16)((u + 0x7FFFu + ((u >> 16) & 1u)) >> 16);
}

// --- kA: 1024 blocks x 256. Wave w -> row pair b*4+w; 32 lanes/row, 8/lane.
// bf16 convert + sq-norms + argmin-key init + ssq per-block partial.
__global__ __launch_bounds__(256) void kA(const float* __restrict__ src,
                                          const float* __restrict__ tgt,
                                          u16* __restrict__ sb, u16* __restrict__ tb,
                                          float* __restrict__ sq,
                                          u32* __restrict__ rowkey,
                                          u32* __restrict__ colkey,
                                          double* __restrict__ accD,
                                          int* __restrict__ cnts,
                                          float* __restrict__ ssqPart) {
    __shared__ float wsA[4];
    int b = blockIdx.x, t = threadIdx.x;
    int w = t >> 6, l = t & 63;
    int r2 = b * 4 + w;                                      // 0..4095: row pair base
    int r = r2 * 2 + (l >> 5);                               // 0..8191
    int lc = (l & 31) * 8;                                   // col 0..248
    const float* row = (r < NS) ? src + (size_t)r * D : tgt + (size_t)(r - NS) * D;
    u16* orow        = (r < NS) ? sb + (size_t)r * D : tb + (size_t)(r - NS) * D;
    float4 v0 = *(const float4*)&row[lc];
    float4 v1 = *(const float4*)&row[lc + 4];
    ushort8v o;
    o.s0 = f2bf(v0.x); o.s1 = f2bf(v0.y); o.s2 = f2bf(v0.z); o.s3 = f2bf(v0.w);
    o.s4 = f2bf(v1.x); o.s5 = f2bf(v1.y); o.s6 = f2bf(v1.z); o.s7 = f2bf(v1.w);
    *(ushort8v*)&orow[lc] = o;
    float s = v0.x * v0.x + v0.y * v0.y + v0.z * v0.z + v0.w * v0.w +
              v1.x * v1.x + v1.y * v1.y + v1.z * v1.z + v1.w * v1.w;
    #pragma unroll
    for (int off = 16; off; off >>= 1) s += __shfl_down(s, off, 64);
    if ((l & 31) == 0) sq[r] = s;

    // per-wave row-norm total (lanes 0 and 32 hold the two row sums)
    float rtot = s + __shfl_down(s, 32, 64);
    if (l == 0) wsA[w] = rtot;

    int gid = b * 256 + t;                                   // 0..262143
    if (gid < NS) rowkey[gid] = 0xFFFFFFFFu;
    else if (gid < 2 * NS) colkey[gid - NS] = 0xFFFFFFFFu;
    if (b == 0) {
        if (t < 8) accD[t] = 0.0;
        else if (t == 8) cnts[0] = 0;
    }
    __syncthreads();
    if (t == 0) ssqPart[b] = wsA[0] + wsA[1] + wsA[2] + wsA[3];  // plain store
}

// --- k3: 128x128 tile/block, 512 threads (8 waves), LDS-staged bf16 MFMA --
// Linear grid: [0,1024) XY full 32x32; [1024,1552) XX upper; [1552,2080) YY.
// Wave (wm,wn) = (w>>2, w&3) owns rows wm*64..+64, cols wn*32..+32:
// acc[4][2] = 32 AGPR/lane. __launch_bounds__(512,4) = 128-reg cap =
// 4 waves/SIMD = 2 blocks/CU = 16 waves/CU (was 12). Spill tripwire: WRITE.
__global__ __launch_bounds__(512, 4) void k3_mfma(const u16* __restrict__ Sb,
                                                  const u16* __restrict__ Tb,
                                                  const float* __restrict__ sq,
                                                  double* __restrict__ accD,
                                                  u32* __restrict__ rowkey,
                                                  u32* __restrict__ colkey,
                                                  const float* __restrict__ ssqPart) {
    int idx = blockIdx.x;
    int bz, ti, tj;
    if (idx < 1024) {
        bz = 0; ti = idx >> 5; tj = idx & 31;
    } else {
        int t = idx - 1024;
        bz = 1;
        if (t >= 528) { t -= 528; bz = 2; }
        // decode upper-tri (i<=j, n=32): largest i with T(i)=i*(65-i)/2 <= t
        int i = (int)((65.0f - sqrtf(4225.0f - 8.0f * (float)t)) * 0.5f);
        if ((i + 1) * (64 - i) / 2 <= t) i++;
        else if (i * (65 - i) / 2 > t) i--;
        ti = i;
        tj = i + (t - i * (65 - i) / 2);
    }

    const u16* Am = (bz == 2) ? Tb : Sb;
    const u16* Bm = (bz == 1) ? Sb : Tb;
    const float* sqA = (bz == 2) ? sq + NS : sq;
    const float* sqB = (bz == 1) ? sq : sq + NS;
    int zacc = (bz == 0) ? 2 : (bz - 1);                     // accD: 0=XX,1=YY,2=XY

    __shared__ __align__(16) u16 Atile[128 * 64];            // 16 KB, 8x16B chunks/row
    __shared__ __align__(16) u16 Btile[128 * 64];            // chunk' = chunk ^ (row&7)
    __shared__ float sqa_s[128], sqb_s[128];
    __shared__ u32 rminL[128], cminL[128];
    __shared__ float wsum[8];
    __shared__ float wssq[4];

    int tid = threadIdx.x;
    int w = tid >> 6, ln = tid & 63;
    int wm = w >> 2, wn = w & 3;                             // 2 x 4 wave grid
    int quad = ln >> 4, lrow = ln & 15;
    int row0 = ti * 128, col0 = tj * 128;

    if (tid < 128)      { sqa_s[tid] = sqA[row0 + tid]; rminL[tid] = 0xFFFFFFFFu; }
    else if (tid < 256) { sqb_s[tid - 128] = sqB[col0 + tid - 128]; cminL[tid - 128] = 0xFFFFFFFFu; }

    // ssq from kA's 1024 per-block partials: waves 0-3 only (1 float4/thread)
    if (tid < 256) {
        float4 pv = *(const float4*)&ssqPart[tid * 4];
        float ssq_p = pv.x + pv.y + pv.z + pv.w;
        #pragma unroll
        for (int off = 32; off; off >>= 1) ssq_p += __shfl_down(ssq_p, off, 64);
        if (ln == 0) wssq[w] = ssq_p;
    }

    // staging lane map: each wave stages 16 rows of A and B per K-step:
    // localrow = w*16 + i*8 + (ln>>3), LDS chunk' = ln&7,
    // global chunk = (ln&7) ^ (ln>>3)  (since localrow&7 == ln>>3)
    int lr8 = ln >> 3;
    int cg  = (ln & 7) ^ lr8;

    floatx4 acc[4][2] = {};

    #pragma unroll
    for (int kc = 0; kc < D; kc += 64) {
        #pragma unroll
        for (int i = 0; i < 2; i++) {
            int lrb = w * 16 + i * 8;
            GLD_LDS16(Am + (size_t)(row0 + lrb + lr8) * D + kc + cg * 8,
                      &Atile[lrb * 64]);
            GLD_LDS16(Bm + (size_t)(col0 + lrb + lr8) * D + kc + cg * 8,
                      &Btile[lrb * 64]);
        }
        __syncthreads();
        // setprio(1) around the MFMA cluster (T5, independent-block shape)
        #pragma unroll
        for (int ks = 0; ks < 2; ks++) {
            int ch = (ks * 4 + quad) ^ (lrow & 7);
            short8 bf2[2];
            #pragma unroll
            for (int cf = 0; cf < 2; cf++)
                bf2[cf] = *(const short8*)&Btile[(wn * 32 + cf * 16 + lrow) * 64 + ch * 8];
            __builtin_amdgcn_s_setprio(1);
            #pragma unroll
            for (int rf = 0; rf < 4; rf++) {
                short8 af = *(const short8*)&Atile[(wm * 64 + rf * 16 + lrow) * 64 + ch * 8];
                #pragma unroll
                for (int cf = 0; cf < 2; cf++)
                    acc[rf][cf] = __builtin_amdgcn_mfma_f32_16x16x32_bf16(
                        af, bf2[cf], acc[rf][cf], 0, 0, 0);
            }
            __builtin_amdgcn_s_setprio(0);
        }
        __syncthreads();
    }

    // ---- epilogue: C/D layout col=lane&15, row=quad*4+reg ----
    // bw = 2n*ssq/(n^2-n)/4; 5 RBF kernels by repeated squaring:
    // t = exp(-l2/(16 bw)); sum t^{1,2,4,8,16}
    // arg = l2*nlog = fma(dot, -2nlog, san+sbn); packed fp32 across reg pairs
    float ssq = wssq[0] + wssq[1] + wssq[2] + wssq[3];
    float bw = (float)(2.0 * 8192.0 * (double)ssq / (8192.0 * 8192.0 - 8192.0) / 4.0);
    float nlog = -1.4426950408889634f / (bw * 16.0f);
    float m2n  = -2.0f * nlog;                               // > 0
    float2v m2n2 = {m2n, m2n};
    float2v tsum2 = {0.f, 0.f};

    float sbn_c[2];
    #pragma unroll
    for (int cf = 0; cf < 2; cf++)
        sbn_c[cf] = sqb_s[wn * 32 + cf * 16 + lrow] * nlog;

    int rbase = row0 + wm * 64, cbase = col0 + wn * 32;

    if (bz == 0) {
        // argmin key from arg = l2*nlog: all args strictly negative, as_uint
        // monotone in l2 -> same argmin (absmax 0.0 since R1).
        u32 ck[2];
        #pragma unroll
        for (int cf = 0; cf < 2; cf++) ck[cf] = 0xFFFFFFFFu;
        #pragma unroll
        for (int rf = 0; rf < 4; rf++) {
            int sA = wm * 64 + rf * 16 + quad * 4;
            int giB = rbase + rf * 16 + quad * 4;
            float2v san01 = {sqa_s[sA + 0] * nlog, sqa_s[sA + 1] * nlog};
            float2v san23 = {sqa_s[sA + 2] * nlog, sqa_s[sA + 3] * nlog};
            u32 rk[4];
            #pragma unroll
            for (int reg = 0; reg < 4; reg++) rk[reg] = 0xFFFFFFFFu;
            #pragma unroll
            for (int cf = 0; cf < 2; cf++) {
                int gj = cbase + cf * 16 + lrow;
                float2v sbv2 = {sbn_c[cf], sbn_c[cf]};
                float2v g01 = acc[rf][cf].xy * m2n2 + (san01 + sbv2);   // v_pk_fma
                float2v g23 = acc[rf][cf].zw * m2n2 + (san23 + sbv2);
                float2v t4a, t4b;
                t4a.x = EXP2F(g01.x); t4a.y = EXP2F(g01.y);
                t4b.x = EXP2F(g23.x); t4b.y = EXP2F(g23.y);
                float2v t3a = t4a * t4a, t2a = t3a * t3a, t1a = t2a * t2a, t0a = t1a * t1a;
                float2v t3b = t4b * t4b, t2b = t3b * t3b, t1b = t2b * t2b, t0b = t1b * t1b;
                tsum2 += ((t0a + t1a) + (t2a + t3a)) + t4a;
                tsum2 += ((t0b + t1b) + (t2b + t3b)) + t4b;
                u32 q0 = __float_as_uint(g01.x) & 0xFFFFF000u;
                u32 q1 = __float_as_uint(g01.y) & 0xFFFFF000u;
                u32 q2 = __float_as_uint(g23.x) & 0xFFFFF000u;
                u32 q3 = __float_as_uint(g23.y) & 0xFFFFF000u;
                rk[0] = min(rk[0], q0 | (u32)gj);
                rk[1] = min(rk[1], q1 | (u32)gj);
                rk[2] = min(rk[2], q2 | (u32)gj);
                rk[3] = min(rk[3], q3 | (u32)gj);
                ck[cf] = min(ck[cf], q0 | (u32)(giB + 0));
                ck[cf] = min(ck[cf], q1 | (u32)(giB + 1));
                ck[cf] = min(ck[cf], q2 | (u32)(giB + 2));
                ck[cf] = min(ck[cf], q3 | (u32)(giB + 3));
            }
            // reduce row-mins across the 16 lanes of each quad (xor 1,2,4,8)
            #pragma unroll
            for (int reg = 0; reg < 4; reg++) {
                u32 v = rk[reg];
                #pragma unroll
                for (int m = 1; m <= 8; m <<= 1)
                    v = min(v, (u32)__shfl_xor((int)v, m, 64));
                if (lrow == 0)
                    atomicMin(&rminL[wm * 64 + rf * 16 + quad * 4 + reg], v);
            }
        }
        // reduce col-mins across the 4 quads (xor 16,32)
        #pragma unroll
        for (int cf = 0; cf < 2; cf++) {
            u32 v = ck[cf];
            v = min(v, (u32)__shfl_xor((int)v, 16, 64));
            v = min(v, (u32)__shfl_xor((int)v, 32, 64));
            if (quad == 0)
                atomicMin(&cminL[wn * 32 + cf * 16 + lrow], v);
        }
    } else if (ti < tj) {
        // off-diagonal tri: every element counts, no predicate, fully packed
        #pragma unroll
        for (int rf = 0; rf < 4; rf++) {
            int sA = wm * 64 + rf * 16 + quad * 4;
            float2v san01 = {sqa_s[sA + 0] * nlog, sqa_s[sA + 1] * nlog};
            float2v san23 = {sqa_s[sA + 2] * nlog, sqa_s[sA + 3] * nlog};
            #pragma unroll
            for (int cf = 0; cf < 2; cf++) {
                float2v sbv2 = {sbn_c[cf], sbn_c[cf]};
                float2v g01 = acc[rf][cf].xy * m2n2 + (san01 + sbv2);
                float2v g23 = acc[rf][cf].zw * m2n2 + (san23 + sbv2);
                float2v t4a, t4b;
                t4a.x = EXP2F(g01.x); t4a.y = EXP2F(g01.y);
                t4b.x = EXP2F(g23.x); t4b.y = EXP2F(g23.y);
                float2v t3a = t4a * t4a, t2a = t3a * t3a, t1a = t2a * t2a, t0a = t1a * t1a;
                float2v t3b = t4b * t4b, t2b = t3b * t3b, t1b = t2b * t2b, t0b = t1b * t1b;
                tsum2 += ((t0a + t1a) + (t2a + t3a)) + t4a;
                tsum2 += ((t0b + t1b) + (t2b + t3b)) + t4b;
            }
        }
    } else {
        // diagonal tri tile (ti==tj, 64 blocks): packed + select-mask mul
        #pragma unroll
        for (int rf = 0; rf < 4; rf++) {
            int sA = wm * 64 + rf * 16 + quad * 4;
            int giB = rbase + rf * 16 + quad * 4;
            float2v san01 = {sqa_s[sA + 0] * nlog, sqa_s[sA + 1] * nlog};
            float2v san23 = {sqa_s[sA + 2] * nlog, sqa_s[sA + 3] * nlog};
            #pragma unroll
            for (int cf = 0; cf < 2; cf++) {
                int gj = cbase + cf * 16 + lrow;
                float2v sbv2 = {sbn_c[cf], sbn_c[cf]};
                float2v g01 = acc[rf][cf].xy * m2n2 + (san01 + sbv2);
                float2v g23 = acc[rf][cf].zw * m2n2 + (san23 + sbv2);
                float2v t4a, t4b;
                t4a.x = EXP2F(g01.x); t4a.y = EXP2F(g01.y);
                t4b.x = EXP2F(g23.x); t4b.y = EXP2F(g23.y);
                float2v t3a = t4a * t4a, t2a = t3a * t3a, t1a = t2a * t2a, t0a = t1a * t1a;
                float2v t3b = t4b * t4b, t2b = t3b * t3b, t1b = t2b * t2b, t0b = t1b * t1b;
                float2v s01 = ((t0a + t1a) + (t2a + t3a)) + t4a;
                float2v s23 = ((t0b + t1b) + (t2b + t3b)) + t4b;
                float2v mk01 = {(giB + 0 < gj) ? 1.f : 0.f, (giB + 1 < gj) ? 1.f : 0.f};
                float2v mk23 = {(giB + 2 < gj) ? 1.f : 0.f, (giB + 3 < gj) ? 1.f : 0.f};
                tsum2 += s01 * mk01;
                tsum2 += s23 * mk23;
            }
        }
    }

    float tsum = tsum2.x + tsum2.y;
    #pragma unroll
    for (int off = 32; off; off >>= 1) tsum += __shfl_down(tsum, off, 64);
    if (ln == 0) wsum[w] = tsum;
    __syncthreads();
    if (tid == 0) {
        float s8 = (wsum[0] + wsum[1]) + (wsum[2] + wsum[3]) +
                   (wsum[4] + wsum[5]) + (wsum[6] + wsum[7]);
        atomicAdd(&accD[zacc], (double)s8);
    }
    if (bz == 0) {
        if (tid < 128)      atomicMin(&rowkey[row0 + tid], rminL[tid]);
        else if (tid < 256) atomicMin(&colkey[col0 + tid - 128], cminL[tid - 128]);
    }
}

// --- k4: 17 blocks x 256. Workers 0..15: CE + distill partials (atomics),
// then barrier-drained counter bump. Block 16: poll counter, finalize out[]
// reading accD via atomic loads only. Handoff ~1us vs ~7-10us for a k5 node.
__global__ __launch_bounds__(256) void k4(const float* __restrict__ sclf,
                                          const float* __restrict__ tclf,
                                          const int* __restrict__ label,
                                          const u32* __restrict__ rowkey,
                                          const u32* __restrict__ colkey,
                                          double* __restrict__ accD,
                                          int* __restrict__ cnts,
                                          float* __restrict__ out) {
    if (blockIdx.x == 16) {               // ---- finalizer poller ----
        if (threadIdx.x == 0) {
            while (atomicAdd(&cnts[0], 0) < 16) __builtin_amdgcn_s_sleep(2);
            double Sxx  = atomicAdd(&accD[0], 0.0);
            double Syy  = atomicAdd(&accD[1], 0.0);
            double Sxy  = atomicAdd(&accD[2], 0.0);
            double clfS = atomicAdd(&accD[3], 0.0);
            double disS = atomicAdd(&accD[4], 0.0);
            double ns = (double)NS;
            out[0] = (float)(clfS / ns);
            out[1] = (float)(disS / ns);
            double sum_xx = 2.0 * Sxx + ns * 5.0;   // diagonal: 5 exps of 0
            double sum_yy = 2.0 * Syy + ns * 5.0;
            out[2] = (float)((sum_xx + sum_yy - 2.0 * Sxy) / (ns * ns));
        }
        return;
    }

    int i = blockIdx.x * 256 + threadIdx.x;   // 0..4095
    float clf, dis = 0.f;

    const float* x = sclf + (size_t)i * C;
    float mx = x[0];
    #pragma unroll
    for (int c = 1; c < C; c++) mx = fmaxf(mx, x[c]);
    float sx = 0.f;
    #pragma unroll
    for (int c = 0; c < C; c++) sx += __expf(x[c] - mx);
    clf = mx + __logf(sx) - x[label[i]];

    {   // teacher = src_clf[i], student = tgt_clf[min_idx[i]]
        int j = (int)(rowkey[i] & 0xFFFu);
        const float* y = tclf + (size_t)j * C;
        float my = y[0];
        #pragma unroll
        for (int c = 1; c < C; c++) my = fmaxf(my, y[c]);
        float sy = 0.f;
        #pragma unroll
        for (int c = 0; c < C; c++) sy += __expf(y[c] - my);
        float dot = 0.f;
        #pragma unroll
        for (int c = 0; c < C; c++) dot += __expf(x[c] - mx) * y[c];
        dis += my + __logf(sy) - dot / sx;
    }
    {   // teacher = src_clf[min_idx_t[i]], student = tgt_clf[i]
        int it = (int)(colkey[i] & 0xFFFu);
        const float* xt = sclf + (size_t)it * C;
        float mt = xt[0];
        #pragma unroll
        for (int c = 1; c < C; c++) mt = fmaxf(mt, xt[c]);
        float st = 0.f;
        #pragma unroll
        for (int c = 0; c < C; c++) st += __expf(xt[c] - mt);
        const float* zz = tclf + (size_t)i * C;
        float mz = zz[0];
        #pragma unroll
        for (int c = 1; c < C; c++) mz = fmaxf(mz, zz[c]);
        float sz = 0.f;
        #pragma unroll
        for (int c = 0; c < C; c++) sz += __expf(zz[c] - mz);
        float dot2 = 0.f;
        #pragma unroll
        for (int c = 0; c < C; c++) dot2 += __expf(xt[c] - mt) * zz[c];
        dis += mz + __logf(sz) - dot2 / st;
    }

    #pragma unroll
    for (int off = 32; off; off >>= 1) {
        clf += __shfl_down(clf, off, 64);
        dis += __shfl_down(dis, off, 64);
    }
    if ((threadIdx.x & 63) == 0) {
        atomicAdd(&accD[3], (double)clf);
        atomicAdd(&accD[4], (double)dis);
    }
    __syncthreads();                      // drains vmcnt: atomics at L2
    if (threadIdx.x == 0) atomicAdd(&cnts[0], 1);
}

extern "C" void kernel_launch(void* const* d_in, const int* in_sizes, int n_in,
                              void* d_out, int out_size, void* d_ws, size_t ws_size,
                              hipStream_t stream) {
    const float* src  = (const float*)d_in[0];   // (4096, 256)
    const float* tgt  = (const float*)d_in[1];   // (4096, 256)
    const float* sclf = (const float*)d_in[2];   // (4096, 6)
    const float* tclf = (const float*)d_in[3];   // (4096, 6)
    const int*   lab  = (const int*)d_in[4];     // (4096,)
    float* out = (float*)d_out;                  // 3 floats

    char* ws = (char*)d_ws;
    u16* sb     = (u16*)ws;                                  // 2 MiB
    u16* tb     = sb + (size_t)NS * D;                       // 2 MiB
    u32* rowkey = (u32*)(ws + 2 * (size_t)NS * D * 2);       // 16 KB
    u32* colkey = rowkey + NS;                               // 16 KB
    float* sq   = (float*)(colkey + NS);                     // 32 KB
    double* accD = (double*)((char*)sq + 2 * NS * 4 + 64);   // 8 doubles
    int* cnts    = (int*)(accD + 8);                         // 1 int
    float* ssqPart = (float*)(accD + 16);                    // 4 KB (1024 f32)

    kA<<<1024, 256, 0, stream>>>(src, tgt, sb, tb, sq, rowkey, colkey, accD, cnts, ssqPart);
    k3_mfma<<<2080, 512, 0, stream>>>(sb, tb, sq, accD, rowkey, colkey, ssqPart);
    k4<<<17, 256, 0, stream>>>(sclf, tclf, lab, rowkey, colkey, accD, cnts, out);
}

// Round 10
// 111.160 us; speedup vs baseline: 1.0600x; 1.0600x over previous
//
#include <hip/hip_runtime.h>
#include <hip/hip_bf16.h>

// ---------------------------------------------------------------------------
// DisNet: clf CE + NN distill + multi-kernel MMD. THREE dispatches, no memset,
// ZERO device fences; cross-kernel visibility = dispatch boundaries.
// FINAL (R10 = revert to R8, best measured: total 112.9us, k3 45.0us).
// ROUND LEDGER (this session) — every lever closed with a measured mechanism:
//   R1 FAILED: (256,4) on 128x128/acc[4][4] -> acc spilled (WRITE 1->107MB).
//   R2 WIN: (256,3) + epilogue cuts (nlog fold, as_uint argmin key) -> 115.7.
//   R3 WIN: packed-fp32 epilogue + ssq hoist + uniform tri branch -> 113.5.
//   R4 FAILED: 128x64 tile -> per-BLOCK fixed overhead doubled per FLOP.
//   R5 FAILED: k4-into-k3 fusion -> extends critical dispatch (46->83us).
//   R6 NEUTRAL-NEG: explicit dbuf BK=32 -> compiler already overlaps; 2x bar.
//   R7 WIN: setprio(1) around MFMA (T5 independent-block shape) -> 111.9.
//   R8 WIN-ish: diag-pack + full K unroll -> k3 45.0us, total 112.9.
//   R9 FAILED: 8-wave 128^2 (512thr, acc[4][2], no spills, occ 22->32%) ->
//     k3 53.5us. DECISIVE: occupancy is NOT the binding constraint; the
//     block-level barrier drain is (8-wave lockstep + doubled per-wave
//     fixed overhead). Latency-bound local optimum reached; remaining gap
//     is barrier structure (all alternatives measured worse) + fixed
//     dispatch overhead (fusion measured worse).
//   kA      : fp32->bf16 convert + row sq-norms + argmin-key inits + per-
//             block ssq partial; block 0 zeroes accD + cnts
//   k3_mfma : pairwise gram, linear 2080-block grid (1024 XY + 528 XX + 528
//             YY upper-tri), LDS staging (global_load_lds w=16, XOR swizzle,
//             0 bank conflicts), MFMA 16x16x32 bf16, packed-fp32 exp-squaring
//             RBF epilogue, packed-u32 argmin, setprio around MFMA.
//   k4      : 17 blocks: 16 workers CE + distill partials (atomics), barrier-
//             drained counter bump; block 16 polls and finalizes out[] via
//             ATOMIC accD reads (per-XCD L2 not coherent for plain loads)
// ---------------------------------------------------------------------------

#define NS 4096
#define D  256
#define C  6

typedef unsigned int u32;
typedef unsigned short u16;
typedef __attribute__((ext_vector_type(8))) short short8;
typedef __attribute__((ext_vector_type(8))) unsigned short ushort8v;
typedef __attribute__((ext_vector_type(4))) float floatx4;
typedef __attribute__((ext_vector_type(2))) float float2v;   // -> v_pk_*_f32

#define EXP2F(x) __builtin_amdgcn_exp2f(x)   // v_exp_f32: D = 2^S0

#define GLD_LDS16(g, l)                                                        \
    __builtin_amdgcn_global_load_lds(                                          \
        (const __attribute__((address_space(1))) unsigned int*)(g),            \
        (__attribute__((address_space(3))) unsigned int*)(l), 16, 0, 0)

__device__ inline u16 f2bf(float f) {
    unsigned u = __float_as_uint(f);
    return (u16)((u + 0x7FFFu + ((u >> 16) & 1u)) >> 16);
}

// --- kA: 1024 blocks x 256. Wave w -> row pair b*4+w; 32 lanes/row, 8/lane.
// bf16 convert + sq-norms + argmin-key init + ssq per-block partial.
__global__ __launch_bounds__(256) void kA(const float* __restrict__ src,
                                          const float* __restrict__ tgt,
                                          u16* __restrict__ sb, u16* __restrict__ tb,
                                          float* __restrict__ sq,
                                          u32* __restrict__ rowkey,
                                          u32* __restrict__ colkey,
                                          double* __restrict__ accD,
                                          int* __restrict__ cnts,
                                          float* __restrict__ ssqPart) {
    __shared__ float wsA[4];
    int b = blockIdx.x, t = threadIdx.x;
    int w = t >> 6, l = t & 63;
    int r2 = b * 4 + w;                                      // 0..4095: row pair base
    int r = r2 * 2 + (l >> 5);                               // 0..8191
    int lc = (l & 31) * 8;                                   // col 0..248
    const float* row = (r < NS) ? src + (size_t)r * D : tgt + (size_t)(r - NS) * D;
    u16* orow        = (r < NS) ? sb + (size_t)r * D : tb + (size_t)(r - NS) * D;
    float4 v0 = *(const float4*)&row[lc];
    float4 v1 = *(const float4*)&row[lc + 4];
    ushort8v o;
    o.s0 = f2bf(v0.x); o.s1 = f2bf(v0.y); o.s2 = f2bf(v0.z); o.s3 = f2bf(v0.w);
    o.s4 = f2bf(v1.x); o.s5 = f2bf(v1.y); o.s6 = f2bf(v1.z); o.s7 = f2bf(v1.w);
    *(ushort8v*)&orow[lc] = o;
    float s = v0.x * v0.x + v0.y * v0.y + v0.z * v0.z + v0.w * v0.w +
              v1.x * v1.x + v1.y * v1.y + v1.z * v1.z + v1.w * v1.w;
    #pragma unroll
    for (int off = 16; off; off >>= 1) s += __shfl_down(s, off, 64);
    if ((l & 31) == 0) sq[r] = s;

    // per-wave row-norm total (lanes 0 and 32 hold the two row sums)
    float rtot = s + __shfl_down(s, 32, 64);
    if (l == 0) wsA[w] = rtot;

    int gid = b * 256 + t;                                   // 0..262143
    if (gid < NS) rowkey[gid] = 0xFFFFFFFFu;
    else if (gid < 2 * NS) colkey[gid - NS] = 0xFFFFFFFFu;
    if (b == 0) {
        if (t < 8) accD[t] = 0.0;
        else if (t == 8) cnts[0] = 0;
    }
    __syncthreads();
    if (t == 0) ssqPart[b] = wsA[0] + wsA[1] + wsA[2] + wsA[3];  // plain store
}

// --- k3: 128x128 tile/block, LDS-staged bf16 MFMA gram + RBF epilogue -----
// Linear grid: [0,1024) XY full 32x32; [1024,1552) XX upper; [1552,2080) YY.
// __launch_bounds__(256,3): 84 VGPR + 64 AGPR fits 3 waves/SIMD; (256,4)
// spills acc to scratch (R1); 8-wave 512thr slower (R9) — do not retry.
__global__ __launch_bounds__(256, 3) void k3_mfma(const u16* __restrict__ Sb,
                                                  const u16* __restrict__ Tb,
                                                  const float* __restrict__ sq,
                                                  double* __restrict__ accD,
                                                  u32* __restrict__ rowkey,
                                                  u32* __restrict__ colkey,
                                                  const float* __restrict__ ssqPart) {
    int idx = blockIdx.x;
    int bz, ti, tj;
    if (idx < 1024) {
        bz = 0; ti = idx >> 5; tj = idx & 31;
    } else {
        int t = idx - 1024;
        bz = 1;
        if (t >= 528) { t -= 528; bz = 2; }
        // decode upper-tri (i<=j, n=32): largest i with T(i)=i*(65-i)/2 <= t
        int i = (int)((65.0f - sqrtf(4225.0f - 8.0f * (float)t)) * 0.5f);
        if ((i + 1) * (64 - i) / 2 <= t) i++;
        else if (i * (65 - i) / 2 > t) i--;
        ti = i;
        tj = i + (t - i * (65 - i) / 2);
    }

    const u16* Am = (bz == 2) ? Tb : Sb;
    const u16* Bm = (bz == 1) ? Sb : Tb;
    const float* sqA = (bz == 2) ? sq + NS : sq;
    const float* sqB = (bz == 1) ? sq : sq + NS;
    int zacc = (bz == 0) ? 2 : (bz - 1);                     // accD: 0=XX,1=YY,2=XY

    __shared__ __align__(16) u16 Atile[128 * 64];            // 16 KB, 8x16B chunks/row
    __shared__ __align__(16) u16 Btile[128 * 64];            // chunk' = chunk ^ (row&7)
    __shared__ float sqa_s[128], sqb_s[128];
    __shared__ u32 rminL[128], cminL[128];
    __shared__ float wsum[4];
    __shared__ float wssq[4];

    int tid = threadIdx.x;
    int w = tid >> 6, ln = tid & 63;
    int wm = w >> 1, wn = w & 1;
    int quad = ln >> 4, lrow = ln & 15;
    int row0 = ti * 128, col0 = tj * 128;

    if (tid < 128) { sqa_s[tid] = sqA[row0 + tid]; rminL[tid] = 0xFFFFFFFFu; }
    else           { sqb_s[tid - 128] = sqB[col0 + tid - 128]; cminL[tid - 128] = 0xFFFFFFFFu; }

    // ssq from kA's 1024 per-block partials: 1 float4/thread + tree
    float4 pv = *(const float4*)&ssqPart[tid * 4];
    float ssq_p = pv.x + pv.y + pv.z + pv.w;
    #pragma unroll
    for (int off = 32; off; off >>= 1) ssq_p += __shfl_down(ssq_p, off, 64);
    if (ln == 0) wssq[w] = ssq_p;

    // staging lane map: localrow = w*32 + i*8 + (ln>>3), LDS chunk' = ln&7,
    // global chunk = (ln&7) ^ (ln>>3)  (since localrow&7 == ln>>3)
    int lr8 = ln >> 3;
    int cg  = (ln & 7) ^ lr8;

    floatx4 acc[4][4] = {};

    #pragma unroll
    for (int kc = 0; kc < D; kc += 64) {
        #pragma unroll
        for (int i = 0; i < 4; i++) {
            int lrb = w * 32 + i * 8;
            GLD_LDS16(Am + (size_t)(row0 + lrb + lr8) * D + kc + cg * 8,
                      &Atile[lrb * 64]);
            GLD_LDS16(Bm + (size_t)(col0 + lrb + lr8) * D + kc + cg * 8,
                      &Btile[lrb * 64]);
        }
        __syncthreads();
        // low fragment liveness: 4 B-frags live, A-frag loaded per-rf.
        // setprio(1) around the MFMA cluster (T5): independent co-resident
        // blocks sit at different phases; favor K-loop waves in arbitration.
        #pragma unroll
        for (int ks = 0; ks < 2; ks++) {
            int ch = (ks * 4 + quad) ^ (lrow & 7);
            short8 bf4[4];
            #pragma unroll
            for (int cf = 0; cf < 4; cf++)
                bf4[cf] = *(const short8*)&Btile[(wn * 64 + cf * 16 + lrow) * 64 + ch * 8];
            __builtin_amdgcn_s_setprio(1);
            #pragma unroll
            for (int rf = 0; rf < 4; rf++) {
                short8 af = *(const short8*)&Atile[(wm * 64 + rf * 16 + lrow) * 64 + ch * 8];
                #pragma unroll
                for (int cf = 0; cf < 4; cf++)
                    acc[rf][cf] = __builtin_amdgcn_mfma_f32_16x16x32_bf16(
                        af, bf4[cf], acc[rf][cf], 0, 0, 0);
            }
            __builtin_amdgcn_s_setprio(0);
        }
        __syncthreads();
    }

    // ---- epilogue: C/D layout col=lane&15, row=quad*4+reg ----
    // bw = 2n*ssq/(n^2-n)/4; 5 RBF kernels by repeated squaring:
    // t = exp(-l2/(16 bw)); sum t^{1,2,4,8,16}
    // arg = l2*nlog = fma(dot, -2nlog, san+sbn); packed fp32 across reg pairs
    float ssq = wssq[0] + wssq[1] + wssq[2] + wssq[3];
    float bw = (float)(2.0 * 8192.0 * (double)ssq / (8192.0 * 8192.0 - 8192.0) / 4.0);
    float nlog = -1.4426950408889634f / (bw * 16.0f);
    float m2n  = -2.0f * nlog;                               // > 0
    float2v m2n2 = {m2n, m2n};
    float2v tsum2 = {0.f, 0.f};

    float sbn_c[4];
    #pragma unroll
    for (int cf = 0; cf < 4; cf++)
        sbn_c[cf] = sqb_s[wn * 64 + cf * 16 + lrow] * nlog;

    int rbase = row0 + wm * 64, cbase = col0 + wn * 64;

    if (bz == 0) {
        // argmin key from arg = l2*nlog: all args strictly negative, as_uint
        // monotone in l2 -> same argmin (absmax 0.0 since R1).
        u32 ck[4];
        #pragma unroll
        for (int cf = 0; cf < 4; cf++) ck[cf] = 0xFFFFFFFFu;
        #pragma unroll
        for (int rf = 0; rf < 4; rf++) {
            int sA = wm * 64 + rf * 16 + quad * 4;
            int giB = rbase + rf * 16 + quad * 4;
            float2v san01 = {sqa_s[sA + 0] * nlog, sqa_s[sA + 1] * nlog};
            float2v san23 = {sqa_s[sA + 2] * nlog, sqa_s[sA + 3] * nlog};
            u32 rk[4];
            #pragma unroll
            for (int reg = 0; reg < 4; reg++) rk[reg] = 0xFFFFFFFFu;
            #pragma unroll
            for (int cf = 0; cf < 4; cf++) {
                int gj = cbase + cf * 16 + lrow;
                float2v sbv2 = {sbn_c[cf], sbn_c[cf]};
                float2v g01 = acc[rf][cf].xy * m2n2 + (san01 + sbv2);   // v_pk_fma
                float2v g23 = acc[rf][cf].zw * m2n2 + (san23 + sbv2);
                float2v t4a, t4b;
                t4a.x = EXP2F(g01.x); t4a.y = EXP2F(g01.y);
                t4b.x = EXP2F(g23.x); t4b.y = EXP2F(g23.y);
                float2v t3a = t4a * t4a, t2a = t3a * t3a, t1a = t2a * t2a, t0a = t1a * t1a;
                float2v t3b = t4b * t4b, t2b = t3b * t3b, t1b = t2b * t2b, t0b = t1b * t1b;
                tsum2 += ((t0a + t1a) + (t2a + t3a)) + t4a;
                tsum2 += ((t0b + t1b) + (t2b + t3b)) + t4b;
                u32 q0 = __float_as_uint(g01.x) & 0xFFFFF000u;
                u32 q1 = __float_as_uint(g01.y) & 0xFFFFF000u;
                u32 q2 = __float_as_uint(g23.x) & 0xFFFFF000u;
                u32 q3 = __float_as_uint(g23.y) & 0xFFFFF000u;
                rk[0] = min(rk[0], q0 | (u32)gj);
                rk[1] = min(rk[1], q1 | (u32)gj);
                rk[2] = min(rk[2], q2 | (u32)gj);
                rk[3] = min(rk[3], q3 | (u32)gj);
                ck[cf] = min(ck[cf], q0 | (u32)(giB + 0));
                ck[cf] = min(ck[cf], q1 | (u32)(giB + 1));
                ck[cf] = min(ck[cf], q2 | (u32)(giB + 2));
                ck[cf] = min(ck[cf], q3 | (u32)(giB + 3));
            }
            // reduce row-mins across the 16 lanes of each quad (xor 1,2,4,8)
            #pragma unroll
            for (int reg = 0; reg < 4; reg++) {
                u32 v = rk[reg];
                #pragma unroll
                for (int m = 1; m <= 8; m <<= 1)
                    v = min(v, (u32)__shfl_xor((int)v, m, 64));
                if (lrow == 0)
                    atomicMin(&rminL[wm * 64 + rf * 16 + quad * 4 + reg], v);
            }
        }
        // reduce col-mins across the 4 quads (xor 16,32)
        #pragma unroll
        for (int cf = 0; cf < 4; cf++) {
            u32 v = ck[cf];
            v = min(v, (u32)__shfl_xor((int)v, 16, 64));
            v = min(v, (u32)__shfl_xor((int)v, 32, 64));
            if (quad == 0)
                atomicMin(&cminL[wn * 64 + cf * 16 + lrow], v);
        }
    } else if (ti < tj) {
        // off-diagonal tri: every element counts, no predicate, fully packed
        #pragma unroll
        for (int rf = 0; rf < 4; rf++) {
            int sA = wm * 64 + rf * 16 + quad * 4;
            float2v san01 = {sqa_s[sA + 0] * nlog, sqa_s[sA + 1] * nlog};
            float2v san23 = {sqa_s[sA + 2] * nlog, sqa_s[sA + 3] * nlog};
            #pragma unroll
            for (int cf = 0; cf < 4; cf++) {
                float2v sbv2 = {sbn_c[cf], sbn_c[cf]};
                float2v g01 = acc[rf][cf].xy * m2n2 + (san01 + sbv2);
                float2v g23 = acc[rf][cf].zw * m2n2 + (san23 + sbv2);
                float2v t4a, t4b;
                t4a.x = EXP2F(g01.x); t4a.y = EXP2F(g01.y);
                t4b.x = EXP2F(g23.x); t4b.y = EXP2F(g23.y);
                float2v t3a = t4a * t4a, t2a = t3a * t3a, t1a = t2a * t2a, t0a = t1a * t1a;
                float2v t3b = t4b * t4b, t2b = t3b * t3b, t1b = t2b * t2b, t0b = t1b * t1b;
                tsum2 += ((t0a + t1a) + (t2a + t3a)) + t4a;
                tsum2 += ((t0b + t1b) + (t2b + t3b)) + t4b;
            }
        }
    } else {
        // diagonal tri tile (ti==tj, 64 blocks): packed + select-mask mul
        #pragma unroll
        for (int rf = 0; rf < 4; rf++) {
            int sA = wm * 64 + rf * 16 + quad * 4;
            int giB = rbase + rf * 16 + quad * 4;
            float2v san01 = {sqa_s[sA + 0] * nlog, sqa_s[sA + 1] * nlog};
            float2v san23 = {sqa_s[sA + 2] * nlog, sqa_s[sA + 3] * nlog};
            #pragma unroll
            for (int cf = 0; cf < 4; cf++) {
                int gj = cbase + cf * 16 + lrow;
                float2v sbv2 = {sbn_c[cf], sbn_c[cf]};
                float2v g01 = acc[rf][cf].xy * m2n2 + (san01 + sbv2);
                float2v g23 = acc[rf][cf].zw * m2n2 + (san23 + sbv2);
                float2v t4a, t4b;
                t4a.x = EXP2F(g01.x); t4a.y = EXP2F(g01.y);
                t4b.x = EXP2F(g23.x); t4b.y = EXP2F(g23.y);
                float2v t3a = t4a * t4a, t2a = t3a * t3a, t1a = t2a * t2a, t0a = t1a * t1a;
                float2v t3b = t4b * t4b, t2b = t3b * t3b, t1b = t2b * t2b, t0b = t1b * t1b;
                float2v s01 = ((t0a + t1a) + (t2a + t3a)) + t4a;
                float2v s23 = ((t0b + t1b) + (t2b + t3b)) + t4b;
                float2v mk01 = {(giB + 0 < gj) ? 1.f : 0.f, (giB + 1 < gj) ? 1.f : 0.f};
                float2v mk23 = {(giB + 2 < gj) ? 1.f : 0.f, (giB + 3 < gj) ? 1.f : 0.f};
                tsum2 += s01 * mk01;
                tsum2 += s23 * mk23;
            }
        }
    }

    float tsum = tsum2.x + tsum2.y;
    #pragma unroll
    for (int off = 32; off; off >>= 1) tsum += __shfl_down(tsum, off, 64);
    if (ln == 0) wsum[w] = tsum;
    __syncthreads();
    if (tid == 0)
        atomicAdd(&accD[zacc], (double)(wsum[0] + wsum[1] + wsum[2] + wsum[3]));
    if (bz == 0) {
        if (tid < 128) atomicMin(&rowkey[row0 + tid], rminL[tid]);
        else           atomicMin(&colkey[col0 + tid - 128], cminL[tid - 128]);
    }
}

// --- k4: 17 blocks x 256. Workers 0..15: CE + distill partials (atomics),
// then barrier-drained counter bump. Block 16: poll counter, finalize out[]
// reading accD via atomic loads only. Handoff ~1us vs ~7-10us for a k5 node.
__global__ __launch_bounds__(256) void k4(const float* __restrict__ sclf,
                                          const float* __restrict__ tclf,
                                          const int* __restrict__ label,
                                          const u32* __restrict__ rowkey,
                                          const u32* __restrict__ colkey,
                                          double* __restrict__ accD,
                                          int* __restrict__ cnts,
                                          float* __restrict__ out) {
    if (blockIdx.x == 16) {               // ---- finalizer poller ----
        if (threadIdx.x == 0) {
            while (atomicAdd(&cnts[0], 0) < 16) __builtin_amdgcn_s_sleep(2);
            double Sxx  = atomicAdd(&accD[0], 0.0);
            double Syy  = atomicAdd(&accD[1], 0.0);
            double Sxy  = atomicAdd(&accD[2], 0.0);
            double clfS = atomicAdd(&accD[3], 0.0);
            double disS = atomicAdd(&accD[4], 0.0);
            double ns = (double)NS;
            out[0] = (float)(clfS / ns);
            out[1] = (float)(disS / ns);
            double sum_xx = 2.0 * Sxx + ns * 5.0;   // diagonal: 5 exps of 0
            double sum_yy = 2.0 * Syy + ns * 5.0;
            out[2] = (float)((sum_xx + sum_yy - 2.0 * Sxy) / (ns * ns));
        }
        return;
    }

    int i = blockIdx.x * 256 + threadIdx.x;   // 0..4095
    float clf, dis = 0.f;

    const float* x = sclf + (size_t)i * C;
    float mx = x[0];
    #pragma unroll
    for (int c = 1; c < C; c++) mx = fmaxf(mx, x[c]);
    float sx = 0.f;
    #pragma unroll
    for (int c = 0; c < C; c++) sx += __expf(x[c] - mx);
    clf = mx + __logf(sx) - x[label[i]];

    {   // teacher = src_clf[i], student = tgt_clf[min_idx[i]]
        int j = (int)(rowkey[i] & 0xFFFu);
        const float* y = tclf + (size_t)j * C;
        float my = y[0];
        #pragma unroll
        for (int c = 1; c < C; c++) my = fmaxf(my, y[c]);
        float sy = 0.f;
        #pragma unroll
        for (int c = 0; c < C; c++) sy += __expf(y[c] - my);
        float dot = 0.f;
        #pragma unroll
        for (int c = 0; c < C; c++) dot += __expf(x[c] - mx) * y[c];
        dis += my + __logf(sy) - dot / sx;
    }
    {   // teacher = src_clf[min_idx_t[i]], student = tgt_clf[i]
        int it = (int)(colkey[i] & 0xFFFu);
        const float* xt = sclf + (size_t)it * C;
        float mt = xt[0];
        #pragma unroll
        for (int c = 1; c < C; c++) mt = fmaxf(mt, xt[c]);
        float st = 0.f;
        #pragma unroll
        for (int c = 0; c < C; c++) st += __expf(xt[c] - mt);
        const float* zz = tclf + (size_t)i * C;
        float mz = zz[0];
        #pragma unroll
        for (int c = 1; c < C; c++) mz = fmaxf(mz, zz[c]);
        float sz = 0.f;
        #pragma unroll
        for (int c = 0; c < C; c++) sz += __expf(zz[c] - mz);
        float dot2 = 0.f;
        #pragma unroll
        for (int c = 0; c < C; c++) dot2 += __expf(xt[c] - mt) * zz[c];
        dis += mz + __logf(sz) - dot2 / st;
    }

    #pragma unroll
    for (int off = 32; off; off >>= 1) {
        clf += __shfl_down(clf, off, 64);
        dis += __shfl_down(dis, off, 64);
    }
    if ((threadIdx.x & 63) == 0) {
        atomicAdd(&accD[3], (double)clf);
        atomicAdd(&accD[4], (double)dis);
    }
    __syncthreads();                      // drains vmcnt: atomics at L2
    if (threadIdx.x == 0) atomicAdd(&cnts[0], 1);
}

extern "C" void kernel_launch(void* const* d_in, const int* in_sizes, int n_in,
                              void* d_out, int out_size, void* d_ws, size_t ws_size,
                              hipStream_t stream) {
    const float* src  = (const float*)d_in[0];   // (4096, 256)
    const float* tgt  = (const float*)d_in[1];   // (4096, 256)
    const float* sclf = (const float*)d_in[2];   // (4096, 6)
    const float* tclf = (const float*)d_in[3];   // (4096, 6)
    const int*   lab  = (const int*)d_in[4];     // (4096,)
    float* out = (float*)d_out;                  // 3 floats

    char* ws = (char*)d_ws;
    u16* sb     = (u16*)ws;                                  // 2 MiB
    u16* tb     = sb + (size_t)NS * D;                       // 2 MiB
    u32* rowkey = (u32*)(ws + 2 * (size_t)NS * D * 2);       // 16 KB
    u32* colkey = rowkey + NS;                               // 16 KB
    float* sq   = (float*)(colkey + NS);                     // 32 KB
    double* accD = (double*)((char*)sq + 2 * NS * 4 + 64);   // 8 doubles
    int* cnts    = (int*)(accD + 8);                         // 1 int
    float* ssqPart = (float*)(accD + 16);                    // 4 KB (1024 f32)

    kA<<<1024, 256, 0, stream>>>(src, tgt, sb, tb, sq, rowkey, colkey, accD, cnts, ssqPart);
    k3_mfma<<<2080, 256, 0, stream>>>(sb, tb, sq, accD, rowkey, colkey, ssqPart);
    k4<<<17, 256, 0, stream>>>(sclf, tclf, lab, rowkey, colkey, accD, cnts, out);
}